// Round 6
// baseline (171.529 us; speedup 1.0000x reference)
//
#include <hip/hip_runtime.h>
#include <cstdint>
#include <cstddef>

typedef __bf16 bf16_t;
typedef __bf16 bf16x8 __attribute__((ext_vector_type(8)));
typedef __bf16 bf16x4 __attribute__((ext_vector_type(4)));
typedef float f32x4 __attribute__((ext_vector_type(4)));
typedef float f32x16 __attribute__((ext_vector_type(16)));
typedef unsigned int u32x4 __attribute__((ext_vector_type(4)));

#define N_SEQ 2048
#define BATCH 2
#define EMB   1024
#define HID   1024
#define NHEAD 16
#define HDIM  64
#define NBROW (N_SEQ * BATCH)   /* 4096 GEMM rows (n*B+b) */
#define ATT_SCALE2 (0.03125f * 1.44269504f)  /* 1/sqrt(1024) * log2(e) */

#define EXP2F(x) __builtin_amdgcn_exp2f(x)   /* __exp2f collides with glibc macro */

static __device__ __forceinline__ void async_copy16(const bf16_t* g, bf16_t* l) {
  __builtin_amdgcn_global_load_lds((const __attribute__((address_space(1))) void*)g,
                                   (__attribute__((address_space(3))) void*)l,
                                   16, 0, 0);
}

// ---------------- fused prep: convert x + transpose both weights -----------
__global__ __launch_bounds__(256) void prep_kernel(
    const float* __restrict__ x, const float* __restrict__ Wp,
    const float* __restrict__ Wo, bf16_t* __restrict__ Xb,
    bf16_t* __restrict__ Wpt, bf16_t* __restrict__ Wot) {
  int bid = blockIdx.x;
  if (bid < 4096) {
    int i = (bid * 256 + threadIdx.x) * 4;
    float4 v = *(const float4*)(x + i);
    bf16x4 o;
    o[0] = (bf16_t)v.x; o[1] = (bf16_t)v.y; o[2] = (bf16_t)v.z; o[3] = (bf16_t)v.w;
    *(bf16x4*)(Xb + i) = o;
    return;
  }
  __shared__ float tile[32][33];
  const float* in; bf16_t* out; int R, C, bx;
  if (bid < 4096 + 3072) { bx = bid - 4096; in = Wp; out = Wpt; R = 1024; C = 3072; }
  else                   { bx = bid - 7168; in = Wo; out = Wot; R = 1024; C = 1024; }
  int gx = C / 32;
  int bc = (bx % gx) * 32, br = (bx / gx) * 32;
  int tx = threadIdx.x & 31, ty = threadIdx.x >> 5;   // 32 x 8
  #pragma unroll
  for (int i = 0; i < 32; i += 8)
    tile[ty + i][tx] = in[(size_t)(br + ty + i) * C + bc + tx];
  __syncthreads();
  #pragma unroll
  for (int i = 0; i < 32; i += 8)
    out[(size_t)(bc + ty + i) * R + br + tx] = (bf16_t)tile[tx][ty + i];
}

// ---------------- pipelined GEMM: C = A * Bt^T + bias ----------------------
// Round-1 verified version (BM=128, BN=128).
template <int BM, int BN, bool OUT_BF16, bool SCALEQ, bool WRITE_VT>
__global__ __launch_bounds__(256) void gemm_bt_kernel(
    const bf16_t* __restrict__ A, const bf16_t* __restrict__ Bt,
    const float* __restrict__ bias, void* __restrict__ Cout,
    bf16_t* __restrict__ Vt, int M, int Nn, int K) {
  constexpr int BK = 64;
  constexpr int MT = BM / 32;
  constexpr int NT = BN / 32;
  constexpr int CA = BM / 32;
  constexpr int CB = BN / 32;
  constexpr int ASZ = BM * BK;
  constexpr int BSZ = BN * BK;
  __shared__ __align__(16) bf16_t smem[2 * ASZ + 2 * BSZ];
  bf16_t* const Asb = smem;
  bf16_t* const Bsb = smem + 2 * ASZ;
  int tid = threadIdx.x;
  int wave = tid >> 6, lane = tid & 63;
  int c = lane & 15, quad = lane >> 4;
  int bm = blockIdx.x * BM;
  int bn = blockIdx.y * BN;
  int wm = (wave & 1) * (BM / 2), wn = (wave >> 1) * (BN / 2);
  f32x4 acc[MT][NT] = {};

  const bf16_t* agp[CA]; int alo[CA];
  const bf16_t* bgp[CB]; int blo[CB];
  #pragma unroll
  for (int i = 0; i < CA; ++i) {
    int p = i * 256 + tid;
    int row = p >> 3, ko = (p & 7) ^ (row & 7);
    agp[i] = A + (size_t)(bm + row) * K + ko * 8;
    alo[i] = (i * 256 + wave * 64) * 8;
  }
  #pragma unroll
  for (int i = 0; i < CB; ++i) {
    int p = i * 256 + tid;
    int row = p >> 3, ko = (p & 7) ^ (row & 7);
    bgp[i] = Bt + (size_t)(bn + row) * K + ko * 8;
    blo[i] = (i * 256 + wave * 64) * 8;
  }

  #pragma unroll
  for (int i = 0; i < CA; ++i) async_copy16(agp[i], Asb + alo[i]);
  #pragma unroll
  for (int i = 0; i < CB; ++i) async_copy16(bgp[i], Bsb + blo[i]);

  int nkb = K / BK;
  for (int ki = 0; ki < nkb; ++ki) {
    __syncthreads();
    if (ki + 1 < nkb) {
      int kb = (ki + 1) * BK;
      bf16_t* an = Asb + ((ki + 1) & 1) * ASZ;
      bf16_t* bnx = Bsb + ((ki + 1) & 1) * BSZ;
      #pragma unroll
      for (int i = 0; i < CA; ++i) async_copy16(agp[i] + kb, an + alo[i]);
      #pragma unroll
      for (int i = 0; i < CB; ++i) async_copy16(bgp[i] + kb, bnx + blo[i]);
    }
    const bf16_t* as = Asb + (ki & 1) * ASZ;
    const bf16_t* bs = Bsb + (ki & 1) * BSZ;
    #pragma unroll
    for (int kk = 0; kk < 2; ++kk) {
      bf16x8 af[MT], bf[NT];
      #pragma unroll
      for (int mt = 0; mt < MT; ++mt) {
        int row = wm + mt * 16 + c;
        int slot = (kk * 4 + quad) ^ (row & 7);
        af[mt] = *(const bf16x8*)(as + (size_t)(row * 8 + slot) * 8);
      }
      #pragma unroll
      for (int nt = 0; nt < NT; ++nt) {
        int row = wn + nt * 16 + c;
        int slot = (kk * 4 + quad) ^ (row & 7);
        bf[nt] = *(const bf16x8*)(bs + (size_t)(row * 8 + slot) * 8);
      }
      #pragma unroll
      for (int mt = 0; mt < MT; ++mt)
        #pragma unroll
        for (int nt = 0; nt < NT; ++nt)
          acc[mt][nt] = __builtin_amdgcn_mfma_f32_16x16x32_bf16(
              af[mt], bf[nt], acc[mt][nt], 0, 0, 0);
    }
  }

  bool do_vt = WRITE_VT && (bn >= 2 * HID);
  bf16_t* tb = smem;
  if (do_vt) __syncthreads();

  #pragma unroll
  for (int nt = 0; nt < NT; ++nt) {
    int col = bn + wn + nt * 16 + c;
    float bv = bias[col];
    float sc = (SCALEQ && col < HID) ? ATT_SCALE2 : 1.0f;
    #pragma unroll
    for (int mt = 0; mt < MT; ++mt) {
      #pragma unroll
      for (int r = 0; r < 4; ++r) {
        int loc = wm + mt * 16 + quad * 4 + r;
        int row = bm + loc;
        float v = (acc[mt][nt][r] + bv) * sc;
        if (OUT_BF16)
          ((bf16_t*)Cout)[(size_t)row * Nn + col] = (bf16_t)v;
        else
          ((float*)Cout)[(size_t)row * Nn + col] = v;
        if (do_vt) {
          int dg = wn + nt * 16 + c;
          int hh = dg >> 6, dl = dg & 63;
          tb[((loc & 1) * 2 + hh) * 4608 + dl * 72 + (loc >> 1)] = (bf16_t)v;
        }
      }
    }
  }

  if (do_vt) {
    __syncthreads();
    int h0 = (bn - 2 * HID) >> 6;
    int n2 = (tid & 7) * 8;
    #pragma unroll
    for (int i = 0; i < 2; ++i) {
      #pragma unroll
      for (int hh = 0; hh < 2; ++hh) {
        #pragma unroll
        for (int k = 0; k < 2; ++k) {
          int d = (tid >> 3) + k * 32;
          bf16x8 vv = *(const bf16x8*)(tb + ((i * 2 + hh) * 4608) + d * 72 + n2);
          *(bf16x8*)(Vt + (size_t)((i * 16 + h0 + hh) * HDIM + d) * N_SEQ + bm / 2 + n2) = vv;
        }
      }
    }
  }
}

// ---------------- flash attention: 32x32 MFMA, register P-exchange ---------
// 4 waves x 32 Q-rows. mfma_f32_32x32x16_bf16 halves LDS bytes per FLOP vs
// 16x16x32 (one 16B frag feeds 32k FLOP). A=K (m=j=lane&31, k=(lane>>5)*8+e),
// B=Q (n=i=lane&31). C/D: col=lane&31=i, row=(reg&3)+8*(reg>>2)+4*(lane>>5)=j
// [m101-verified]. P->PV B-frag redistribution is a pure lane+-32 exchange:
// frag = [own low-pack, partner low-pack] (half0) / [partner high, own high]
// (half1) via __shfl_xor(32) + select. No P LDS buffer: LDS = 32KB.
__global__ __launch_bounds__(256, 3) void flash_attn_kernel(
    const bf16_t* __restrict__ Pj, const bf16_t* __restrict__ Vt,
    bf16_t* __restrict__ AO) {
  __shared__ __align__(16) bf16_t Ks[2][64 * 64];   // [j][d] swizzled
  __shared__ __align__(16) bf16_t Vs[2][64 * 64];   // [d][j] swizzled
  const int PJP = 3 * HID;
  int tid = threadIdx.x, wave = tid >> 6, lane = tid & 63;
  int il = lane & 31, half = lane >> 5;
  int bid = blockIdx.x;
  int qb = (bid < 256) ? (15 - (bid >> 5)) : ((bid - 256) >> 5);
  int bh = bid & 31;
  int h = bh & 15, b = bh >> 4;
  int i0 = qb * 128;
  int irow = i0 + wave * 32 + il;     // this lane's Q row
  int imax = i0 + wave * 32 + 31;     // wave's last Q row

  // Q B-frags: qf[s] holds Q[irow][s*16 + half*8 .. +8]
  bf16x8 qf[4];
  {
    const bf16_t* qg = Pj + (size_t)(irow * BATCH + b) * PJP + h * HDIM + half * 8;
    #pragma unroll
    for (int s = 0; s < 4; ++s) qf[s] = *(const bf16x8*)(qg + s * 16);
  }

  f32x16 o0 = {}, o1 = {};           // O^T rows d (0-31 / 32-63), col i
  float lrow = 0.f;

  // staging: each thread stores rows jr & jr+32 at octet oc (0-conflict:
  // quarter-wave covers rows 0..1 x octets 0..7 -> 2-way only)
  int jr = tid >> 3, oc = tid & 7;
  int sl = (oc ^ (jr & 7)) * 8;      // (jr+32)&7 == jr&7
  int lo0 = jr * 64 + sl;
  int lo1 = (jr + 32) * 64 + sl;
  const bf16_t* kg = Pj + (size_t)b * PJP + HID + h * HDIM + oc * 8;
  const bf16_t* vg  = Vt + (size_t)(bh * HDIM + jr) * N_SEQ + oc * 8;
  const bf16_t* vg2 = Vt + (size_t)(bh * HDIM + jr + 32) * N_SEQ + oc * 8;

  int njt = 2 * qb + 2;
  bf16x8 k0 = *(const bf16x8*)(kg + (size_t)jr * BATCH * PJP);
  bf16x8 k1 = *(const bf16x8*)(kg + (size_t)(jr + 32) * BATCH * PJP);
  bf16x8 v0 = *(const bf16x8*)(vg);
  bf16x8 v1 = *(const bf16x8*)(vg2);

  int rx = il & 7;
  bool hb = (half != 0);

  for (int jt = 0; jt < njt; ++jt) {
    bf16_t* ks = Ks[jt & 1];
    bf16_t* vs = Vs[jt & 1];
    *(bf16x8*)(ks + lo0) = k0;
    *(bf16x8*)(ks + lo1) = k1;
    *(bf16x8*)(vs + lo0) = v0;
    *(bf16x8*)(vs + lo1) = v1;
    __syncthreads();
    if (jt + 1 < njt) {
      int j0n = (jt + 1) * 64;
      k0 = *(const bf16x8*)(kg + (size_t)(j0n + jr) * BATCH * PJP);
      k1 = *(const bf16x8*)(kg + (size_t)(j0n + jr + 32) * BATCH * PJP);
      v0 = *(const bf16x8*)(vg + j0n);
      v1 = *(const bf16x8*)(vg2 + j0n);
    }

    if (jt * 64 <= imax) {           // skip fully-masked tiles for this wave
      // ---- QK^T: st0 = S[j=0..31][i], st1 = S[j=32..63][i] ----
      f32x16 st0 = {}, st1 = {};
      __builtin_amdgcn_s_setprio(1);
      #pragma unroll
      for (int s = 0; s < 4; ++s) {
        bf16x8 ka = *(const bf16x8*)(ks + il * 64 + (((half + 2 * s) & 7) ^ rx) * 8);
        st0 = __builtin_amdgcn_mfma_f32_32x32x16_bf16(ka, qf[s], st0, 0, 0, 0);
      }
      #pragma unroll
      for (int s = 0; s < 4; ++s) {
        bf16x8 ka = *(const bf16x8*)(ks + (32 + il) * 64 + (((half + 2 * s) & 7) ^ rx) * 8);
        st1 = __builtin_amdgcn_mfma_f32_32x32x16_bf16(ka, qf[s], st1, 0, 0, 0);
      }
      __builtin_amdgcn_s_setprio(0);

      if (jt >= 2 * qb) {            // diagonal tiles: causal mask
        int j0 = jt * 64;
        #pragma unroll
        for (int r = 0; r < 16; ++r) {
          int jrow = (r & 3) + 8 * (r >> 2) + 4 * half;
          if (j0 + jrow > irow)      st0[r] = -1e30f;
          if (j0 + 32 + jrow > irow) st1[r] = -1e30f;
        }
      }

      #pragma unroll
      for (int r = 0; r < 16; ++r) {
        st0[r] = EXP2F(st0[r]); lrow += st0[r];
        st1[r] = EXP2F(st1[r]); lrow += st1[r];
      }

      // ---- pack P into PV B-frags (lane+-32 exchange, no LDS) ----
      unsigned int fr[4][4];
      #pragma unroll
      for (int t = 0; t < 2; ++t) {
        {
          unsigned int lw0, lw1, hw0, hw1;
          {
            unsigned short a0 = __builtin_bit_cast(unsigned short, (bf16_t)st0[8*t+0]);
            unsigned short a1 = __builtin_bit_cast(unsigned short, (bf16_t)st0[8*t+1]);
            unsigned short a2 = __builtin_bit_cast(unsigned short, (bf16_t)st0[8*t+2]);
            unsigned short a3 = __builtin_bit_cast(unsigned short, (bf16_t)st0[8*t+3]);
            unsigned short a4 = __builtin_bit_cast(unsigned short, (bf16_t)st0[8*t+4]);
            unsigned short a5 = __builtin_bit_cast(unsigned short, (bf16_t)st0[8*t+5]);
            unsigned short a6 = __builtin_bit_cast(unsigned short, (bf16_t)st0[8*t+6]);
            unsigned short a7 = __builtin_bit_cast(unsigned short, (bf16_t)st0[8*t+7]);
            lw0 = (unsigned int)a0 | ((unsigned int)a1 << 16);
            lw1 = (unsigned int)a2 | ((unsigned int)a3 << 16);
            hw0 = (unsigned int)a4 | ((unsigned int)a5 << 16);
            hw1 = (unsigned int)a6 | ((unsigned int)a7 << 16);
          }
          unsigned int pl0 = (unsigned int)__shfl_xor((int)lw0, 32);
          unsigned int pl1 = (unsigned int)__shfl_xor((int)lw1, 32);
          unsigned int ph0 = (unsigned int)__shfl_xor((int)hw0, 32);
          unsigned int ph1 = (unsigned int)__shfl_xor((int)hw1, 32);
          fr[t][0] = hb ? ph0 : lw0;
          fr[t][1] = hb ? ph1 : lw1;
          fr[t][2] = hb ? hw0 : pl0;
          fr[t][3] = hb ? hw1 : pl1;
        }
        {
          unsigned int lw0, lw1, hw0, hw1;
          {
            unsigned short a0 = __builtin_bit_cast(unsigned short, (bf16_t)st1[8*t+0]);
            unsigned short a1 = __builtin_bit_cast(unsigned short, (bf16_t)st1[8*t+1]);
            unsigned short a2 = __builtin_bit_cast(unsigned short, (bf16_t)st1[8*t+2]);
            unsigned short a3 = __builtin_bit_cast(unsigned short, (bf16_t)st1[8*t+3]);
            unsigned short a4 = __builtin_bit_cast(unsigned short, (bf16_t)st1[8*t+4]);
            unsigned short a5 = __builtin_bit_cast(unsigned short, (bf16_t)st1[8*t+5]);
            unsigned short a6 = __builtin_bit_cast(unsigned short, (bf16_t)st1[8*t+6]);
            unsigned short a7 = __builtin_bit_cast(unsigned short, (bf16_t)st1[8*t+7]);
            lw0 = (unsigned int)a0 | ((unsigned int)a1 << 16);
            lw1 = (unsigned int)a2 | ((unsigned int)a3 << 16);
            hw0 = (unsigned int)a4 | ((unsigned int)a5 << 16);
            hw1 = (unsigned int)a6 | ((unsigned int)a7 << 16);
          }
          unsigned int pl0 = (unsigned int)__shfl_xor((int)lw0, 32);
          unsigned int pl1 = (unsigned int)__shfl_xor((int)lw1, 32);
          unsigned int ph0 = (unsigned int)__shfl_xor((int)hw0, 32);
          unsigned int ph1 = (unsigned int)__shfl_xor((int)hw1, 32);
          fr[2 + t][0] = hb ? ph0 : lw0;
          fr[2 + t][1] = hb ? ph1 : lw1;
          fr[2 + t][2] = hb ? hw0 : pl0;
          fr[2 + t][3] = hb ? hw1 : pl1;
        }
      }

      // ---- PV: o = V^T . P ----
      __builtin_amdgcn_s_setprio(1);
      #pragma unroll
      for (int s = 0; s < 4; ++s) {
        u32x4 w = {fr[s][0], fr[s][1], fr[s][2], fr[s][3]};
        bf16x8 pb = __builtin_bit_cast(bf16x8, w);
        bf16x8 va0 = *(const bf16x8*)(vs + il * 64 + (((half + 2 * s) & 7) ^ rx) * 8);
        bf16x8 va1 = *(const bf16x8*)(vs + (32 + il) * 64 + (((half + 2 * s) & 7) ^ rx) * 8);
        o0 = __builtin_amdgcn_mfma_f32_32x32x16_bf16(va0, pb, o0, 0, 0, 0);
        o1 = __builtin_amdgcn_mfma_f32_32x32x16_bf16(va1, pb, o1, 0, 0, 0);
      }
      __builtin_amdgcn_s_setprio(0);
    }
  }

  lrow += __shfl_xor(lrow, 32);
  float linv = 1.0f / lrow;
  int orow = irow * BATCH + b;
  bf16_t* ao = AO + (size_t)orow * HID + h * HDIM;
  #pragma unroll
  for (int t = 0; t < 4; ++t) {
    bf16x4 pv0, pv1;
    #pragma unroll
    for (int r2 = 0; r2 < 4; ++r2) {
      pv0[r2] = (bf16_t)(o0[t * 4 + r2] * linv);
      pv1[r2] = (bf16_t)(o1[t * 4 + r2] * linv);
    }
    int d0 = t * 8 + 4 * half;
    *(bf16x4*)(ao + d0) = pv0;
    *(bf16x4*)(ao + 32 + d0) = pv1;
  }
}

extern "C" void kernel_launch(void* const* d_in, const int* in_sizes, int n_in,
                              void* d_out, int out_size, void* d_ws, size_t ws_size,
                              hipStream_t stream) {
  const float* x      = (const float*)d_in[0];   // [2048][2][1024]
  const float* W_proj = (const float*)d_in[1];   // [1024][3072]
  const float* b_proj = (const float*)d_in[2];   // [3072]
  const float* W_out  = (const float*)d_in[3];   // [1024][1024]
  const float* b_out  = (const float*)d_in[4];   // [1024]

  bf16_t* Xb  = (bf16_t*)d_ws;                               // 4096*1024
  bf16_t* Wpt = Xb  + (size_t)NBROW * EMB;                   // 3072*1024
  bf16_t* Wot = Wpt + (size_t)3 * HID * EMB;                 // 1024*1024
  bf16_t* Pj  = Wot + (size_t)HID * EMB;                     // 4096*3072
  bf16_t* AO  = Pj  + (size_t)NBROW * 3 * HID;               // 4096*1024
  bf16_t* Vt  = AO  + (size_t)NBROW * HID;                   // 32*64*2048

  prep_kernel<<<8192, 256, 0, stream>>>(x, W_proj, W_out, Xb, Wpt, Wot);
  gemm_bt_kernel<128, 128, true, true, true>
      <<<dim3(NBROW / 128, 3 * HID / 128), 256, 0, stream>>>(
      Xb, Wpt, b_proj, (void*)Pj, Vt, NBROW, 3 * HID, EMB);
  flash_attn_kernel<<<512, 256, 0, stream>>>(Pj, Vt, AO);
  gemm_bt_kernel<128, 128, false, false, false>
      <<<dim3(NBROW / 128, EMB / 128), 256, 0, stream>>>(
      AO, Wot, b_out, d_out, nullptr, NBROW, EMB, HID);
}